// Round 1
// baseline (12029.530 us; speedup 1.0000x reference)
//
#include <hip/hip_runtime.h>

typedef unsigned short u16;
typedef unsigned int u32;
typedef unsigned long long u64;
typedef __attribute__((ext_vector_type(8))) short short8;
typedef __attribute__((ext_vector_type(4))) float f32x4;

// ---------- helpers ----------
__device__ __forceinline__ u16 f2bf(float f) {
    u32 u = __float_as_uint(f);
    u32 r = (u + 0x7fffu + ((u >> 16) & 1u)) >> 16;
    return (u16)r;
}
__device__ __forceinline__ float bfl(u32 u) { return __uint_as_float(u << 16); }
__device__ __forceinline__ float bfh(u32 u) { return __uint_as_float(u & 0xffff0000u); }
__device__ __forceinline__ u32 pk2(float a, float b) {
    return (u32)f2bf(a) | ((u32)f2bf(b) << 16);
}

// ---------- constants ----------
#define S_TOT 5120
#define T_DEC 1024
#define S_ENC 4096
#define HDIM 512
#define DDIM 608
#define G4 2048
#define NLOC 50000
#define KFC 1088

// ---------- init: zero broadcast buffers ----------
__global__ void k_init(u64* he, u64* hd) {
    int i = blockIdx.x * 256 + threadIdx.x;
    if (i < 512) { he[i] = 0ull; hd[i] = 0ull; }
}

// ---------- combined biases ----------
__global__ void k_bias(const float* a, const float* b, const float* c, const float* d,
                       float* be, float* bd) {
    int i = blockIdx.x * 256 + threadIdx.x;
    if (i < G4) { be[i] = a[i] + b[i]; bd[i] = c[i] + d[i]; }
}

// ---------- embedding gather + concat -> bf16 x [5120][608] ----------
__global__ __launch_bounds__(256) void k_embed(const int* __restrict__ loc, const int* __restrict__ tim,
    const int* __restrict__ clu, const float* __restrict__ el, const float* __restrict__ et,
    const float* __restrict__ ec, u16* __restrict__ xb) {
    const int s = blockIdx.x;
    const int ls = loc[s], lt = tim[s], lc = clu[s];
    for (int c = threadIdx.x; c < DDIM; c += 256) {
        float v;
        if (c < 512)       v = el[(size_t)ls * 512 + c];
        else if (c < 544)  v = et[lt * 32 + (c - 512)];
        else               v = ec[lc * 64 + (c - 544)];
        xb[(size_t)s * DDIM + c] = f2bf(v);
    }
}

// ---------- GEMM: C[M,N] = A[M,K](bf16) * Bt[N,K]^T (+bias per-n) ----------
// Bt is bf16 (BF32=false) or fp32 converted during staging (BF32=true).
// M%128==0, K%32==0; N guarded (B rows >= N read as 0, stores masked).
template <bool BF32>
__global__ __launch_bounds__(256) void gemm_bt(
    const u16* __restrict__ A, const void* __restrict__ Bv, float* __restrict__ C,
    const float* __restrict__ bias, int N, int K, int lda, int ldb, int ldc) {
    __shared__ u16 As[128][40];
    __shared__ u16 Bs[128][40];
    const int tid = threadIdx.x;
    const int bn = blockIdx.x, bm = blockIdx.y;
    const int wave = tid >> 6, lane = tid & 63;
    const int quad = lane >> 4, l16 = lane & 15;
    const int wm = (wave & 1) << 6, wn = (wave >> 1) << 6;
    const int rq = tid >> 2, q4 = tid & 3;

    f32x4 acc[4][4] = {};

    const u16* Arow0 = A + (size_t)(bm * 128 + rq) * lda + q4 * 8;
    const u16* Arow1 = Arow0 + (size_t)64 * lda;

    const int rb0 = bn * 128 + rq, rb1 = rb0 + 64;
    const bool okb0 = rb0 < N, okb1 = rb1 < N;
    const float* Bf0 = nullptr; const float* Bf1 = nullptr;
    const u16* Bh0 = nullptr; const u16* Bh1 = nullptr;
    if constexpr (BF32) {
        const float* Bf = (const float*)Bv;
        Bf0 = Bf + (size_t)rb0 * ldb + q4 * 8;
        Bf1 = Bf + (size_t)rb1 * ldb + q4 * 8;
    } else {
        const u16* Bh = (const u16*)Bv;
        Bh0 = Bh + (size_t)rb0 * ldb + q4 * 8;
        Bh1 = Bh + (size_t)rb1 * ldb + q4 * 8;
    }

    uint4 a0, a1, bh0, bh1;
    float4 f00, f01, f10, f11;
    const float4 fz = make_float4(0.f, 0.f, 0.f, 0.f);
    auto fetch = [&](int k0) {
        a0 = *(const uint4*)(Arow0 + k0);
        a1 = *(const uint4*)(Arow1 + k0);
        if constexpr (BF32) {
            f00 = okb0 ? *(const float4*)(Bf0 + k0) : fz;
            f01 = okb0 ? *(const float4*)(Bf0 + k0 + 4) : fz;
            f10 = okb1 ? *(const float4*)(Bf1 + k0) : fz;
            f11 = okb1 ? *(const float4*)(Bf1 + k0 + 4) : fz;
        } else {
            bh0 = *(const uint4*)(Bh0 + k0);
            bh1 = *(const uint4*)(Bh1 + k0);
        }
    };
    fetch(0);
    for (int k0 = 0; k0 < K; k0 += 32) {
        __syncthreads();
        *(uint4*)&As[rq][q4 * 8] = a0;
        *(uint4*)&As[rq + 64][q4 * 8] = a1;
        if constexpr (BF32) {
            uint4 t0, t1;
            t0.x = pk2(f00.x, f00.y); t0.y = pk2(f00.z, f00.w);
            t0.z = pk2(f01.x, f01.y); t0.w = pk2(f01.z, f01.w);
            t1.x = pk2(f10.x, f10.y); t1.y = pk2(f10.z, f10.w);
            t1.z = pk2(f11.x, f11.y); t1.w = pk2(f11.z, f11.w);
            *(uint4*)&Bs[rq][q4 * 8] = t0;
            *(uint4*)&Bs[rq + 64][q4 * 8] = t1;
        } else {
            *(uint4*)&Bs[rq][q4 * 8] = bh0;
            *(uint4*)&Bs[rq + 64][q4 * 8] = bh1;
        }
        __syncthreads();
        if (k0 + 32 < K) fetch(k0 + 32);
        short8 af[4], bf[4];
#pragma unroll
        for (int i = 0; i < 4; i++) af[i] = *(const short8*)&As[wm + 16 * i + l16][quad * 8];
#pragma unroll
        for (int j = 0; j < 4; j++) bf[j] = *(const short8*)&Bs[wn + 16 * j + l16][quad * 8];
#pragma unroll
        for (int i = 0; i < 4; i++)
#pragma unroll
            for (int j = 0; j < 4; j++)
                acc[i][j] = __builtin_amdgcn_mfma_f32_16x16x32_bf16(af[i], bf[j], acc[i][j], 0, 0, 0);
    }
#pragma unroll
    for (int j = 0; j < 4; j++) {
        int c0 = bn * 128 + wn + 16 * j + l16;
        if (c0 >= N) continue;
        float bv = bias ? bias[c0] : 0.f;
#pragma unroll
        for (int i = 0; i < 4; i++) {
            int r0 = bm * 128 + wm + 16 * i + quad * 4;
#pragma unroll
            for (int rg = 0; rg < 4; rg++)
                C[(size_t)(r0 + rg) * ldc + c0] = acc[i][j][rg] + bv;
        }
    }
}

// ---------- persistent LSTM: blocks 0-63 encoder, 64-127 decoder ----------
// Each WG owns h[j0..j0+8) and the 32 matching gate rows (bf16 in LDS).
// h broadcast via tagged u64 agent-scope atomics: {tag=t+1, bits(h)}.
__global__ __launch_bounds__(256) void k_lstm(
    const float* __restrict__ Whh_e, const float* __restrict__ Whh_d,
    const float* __restrict__ XW,
    u64* __restrict__ hbc_e, u64* __restrict__ hbc_d,
    u16* __restrict__ Hh, u16* __restrict__ HhT, u16* __restrict__ OutA) {
    __shared__ u16 Wl[32][520];
    __shared__ float hbuf[512];
    __shared__ float gbuf[32];
    __shared__ float cbuf[8];
    const int tid = threadIdx.x;
    const bool enc = (blockIdx.x < 64);
    const int w = enc ? blockIdx.x : (blockIdx.x - 64);
    const int steps = enc ? S_ENC : T_DEC;
    const int j0 = w << 3;
    const float* Whh = enc ? Whh_e : Whh_d;
    u64* hbc = enc ? hbc_e : hbc_d;
    const float* XWb = XW + (enc ? (size_t)0 : (size_t)S_ENC * G4);
    const int r = tid >> 3, c8 = tid & 7;
    // stage this WG's 32 gate rows as bf16
    {
        const int grow = ((r >> 3) << 9) + j0 + (r & 7);
        const float* src = Whh + (size_t)grow * HDIM + c8 * 64;
        u16* dst = &Wl[r][c8 * 64];
        for (int i = 0; i < 64; i += 4) {
            float4 v = *(const float4*)(src + i);
            dst[i] = f2bf(v.x); dst[i + 1] = f2bf(v.y);
            dst[i + 2] = f2bf(v.z); dst[i + 3] = f2bf(v.w);
        }
    }
    if (tid < 8) cbuf[tid] = 0.f;
    const int xw_col = ((r >> 3) << 9) + j0 + (r & 7);
    const int i0 = tid * 2;
    for (int t = 0; t < steps; ++t) {
        float xwv = 0.f;
        if (c8 == 0) xwv = XWb[(size_t)t * G4 + xw_col];  // independent: issues before poll
        int dead = 0, spins = 0;
        u64 v0, v1;
        for (;;) {
            v0 = __hip_atomic_load(&hbc[i0], __ATOMIC_RELAXED, __HIP_MEMORY_SCOPE_AGENT);
            v1 = __hip_atomic_load(&hbc[i0 + 1], __ATOMIC_RELAXED, __HIP_MEMORY_SCOPE_AGENT);
            if ((u32)(v0 >> 32) == (u32)t && (u32)(v1 >> 32) == (u32)t) break;
            if (++spins > (1 << 18)) { dead = 1; break; }
        }
        hbuf[i0] = __uint_as_float((u32)v0);
        hbuf[i0 + 1] = __uint_as_float((u32)v1);
        if (__syncthreads_or(dead)) break;  // WG-uniform bail (no hang)
        float acc = 0.f;
        {
            const u16* wr = &Wl[r][c8 * 64];
            const float* hb = &hbuf[c8 * 64];
#pragma unroll
            for (int i = 0; i < 64; i += 8) {
                uint4 wv = *(const uint4*)(wr + i);
                float4 h0 = *(const float4*)(hb + i);
                float4 h1 = *(const float4*)(hb + i + 4);
                acc += bfl(wv.x) * h0.x; acc += bfh(wv.x) * h0.y;
                acc += bfl(wv.y) * h0.z; acc += bfh(wv.y) * h0.w;
                acc += bfl(wv.z) * h1.x; acc += bfh(wv.z) * h1.y;
                acc += bfl(wv.w) * h1.z; acc += bfh(wv.w) * h1.w;
            }
        }
        acc += __shfl_xor(acc, 1);
        acc += __shfl_xor(acc, 2);
        acc += __shfl_xor(acc, 4);
        if (c8 == 0) gbuf[r] = acc + xwv;
        __syncthreads();
        if (tid < 8) {
            const int j = tid;
            float gi = gbuf[j], gf = gbuf[8 + j], gg = gbuf[16 + j], go = gbuf[24 + j];
            float si = 1.f / (1.f + __expf(-gi));
            float sf = 1.f / (1.f + __expf(-gf));
            float so = 1.f / (1.f + __expf(-go));
            float cc = sf * cbuf[j] + si * tanhf(gg);
            cbuf[j] = cc;
            float h = so * tanhf(cc);
            u16 hb16 = f2bf(h);
            if (enc) {
                Hh[(size_t)t * HDIM + j0 + j] = hb16;
                HhT[(size_t)(j0 + j) * S_ENC + t] = hb16;
            } else {
                OutA[(size_t)t * KFC + j0 + j] = hb16;
            }
            u64 pk = ((u64)(u32)(t + 1) << 32) | (u64)__float_as_uint(h);
            __hip_atomic_store(&hbc[j0 + j], pk, __ATOMIC_RELAXED, __HIP_MEMORY_SCOPE_AGENT);
        }
    }
}

// ---------- row softmax [1024][4096] fp32 -> bf16 ----------
__global__ __launch_bounds__(256) void k_softmax(const float* __restrict__ scores, u16* __restrict__ attn) {
    __shared__ float red[8];
    const int t = blockIdx.x, tid = threadIdx.x;
    const float* row = scores + (size_t)t * S_ENC;
    float v[16];
    float m = -3.4e38f;
#pragma unroll
    for (int j = 0; j < 16; ++j) { v[j] = row[tid + 256 * j]; m = fmaxf(m, v[j]); }
    for (int o = 32; o; o >>= 1) m = fmaxf(m, __shfl_xor(m, o));
    if ((tid & 63) == 0) red[tid >> 6] = m;
    __syncthreads();
    m = fmaxf(fmaxf(red[0], red[1]), fmaxf(red[2], red[3]));
    float s = 0.f;
#pragma unroll
    for (int j = 0; j < 16; ++j) { v[j] = __expf(v[j] - m); s += v[j]; }
    for (int o = 32; o; o >>= 1) s += __shfl_xor(s, o);
    if ((tid & 63) == 0) red[4 + (tid >> 6)] = s;
    __syncthreads();
    const float inv = 1.f / (red[4] + red[5] + red[6] + red[7]);
    u16* orow = attn + (size_t)t * S_ENC;
#pragma unroll
    for (int j = 0; j < 16; ++j) orow[tid + 256 * j] = f2bf(v[j] * inv);
}

// ---------- finish concat: context + uid emb -> OutA cols 512..1088 ----------
__global__ void k_finish(const float* __restrict__ ctx, const float* __restrict__ eu,
                         const int* __restrict__ uid, u16* __restrict__ OutA) {
    const int t = blockIdx.x;
    const int u = uid[0];
    for (int c = threadIdx.x; c < 576; c += 256) {
        float v = (c < 512) ? ctx[(size_t)t * 512 + c] : eu[(size_t)u * 64 + (c - 512)];
        OutA[(size_t)t * KFC + 512 + c] = f2bf(v);
    }
}

// ---------- in-place row log-softmax [1024][50000] ----------
__global__ __launch_bounds__(256) void k_logsoftmax(float* __restrict__ y) {
    __shared__ float red[8];
    const int t = blockIdx.x, tid = threadIdx.x;
    float* row = y + (size_t)t * NLOC;
    float m = -3.4e38f;
    for (int i = tid; i < NLOC; i += 256) m = fmaxf(m, row[i]);
    for (int o = 32; o; o >>= 1) m = fmaxf(m, __shfl_xor(m, o));
    if ((tid & 63) == 0) red[tid >> 6] = m;
    __syncthreads();
    m = fmaxf(fmaxf(red[0], red[1]), fmaxf(red[2], red[3]));
    float s = 0.f;
    for (int i = tid; i < NLOC; i += 256) s += __expf(row[i] - m);
    for (int o = 32; o; o >>= 1) s += __shfl_xor(s, o);
    if ((tid & 63) == 0) red[4 + (tid >> 6)] = s;
    __syncthreads();
    const float lse = m + __logf(red[4] + red[5] + red[6] + red[7]);
    for (int i = tid; i < NLOC; i += 256) row[i] -= lse;
}

extern "C" void kernel_launch(void* const* d_in, const int* in_sizes, int n_in,
                              void* d_out, int out_size, void* d_ws, size_t ws_size,
                              hipStream_t stream) {
    const int* loc = (const int*)d_in[0];
    const int* tim = (const int*)d_in[1];
    const int* clu = (const int*)d_in[2];
    const int* uid = (const int*)d_in[3];
    const float* emb_loc = (const float*)d_in[5];
    const float* emb_tim = (const float*)d_in[6];
    const float* emb_clu = (const float*)d_in[7];
    const float* emb_uid = (const float*)d_in[8];
    const float* enc_Wih = (const float*)d_in[9];
    const float* enc_Whh = (const float*)d_in[10];
    const float* enc_bih = (const float*)d_in[11];
    const float* enc_bhh = (const float*)d_in[12];
    const float* dec_Wih = (const float*)d_in[13];
    const float* dec_Whh = (const float*)d_in[14];
    const float* dec_bih = (const float*)d_in[15];
    const float* dec_bhh = (const float*)d_in[16];
    const float* fcW = (const float*)d_in[17];
    const float* fcb = (const float*)d_in[18];
    float* out = (float*)d_out;

    char* p = (char*)d_ws;
    auto alloc = [&](size_t bytes) -> void* {
        void* r = (void*)p;
        p += (bytes + 255) & ~(size_t)255;
        return r;
    };
    u16* xb      = (u16*)alloc((size_t)S_TOT * DDIM * 2);
    float* XW    = (float*)alloc((size_t)S_TOT * G4 * 4);
    float* bias_e = (float*)alloc(G4 * 4);
    float* bias_d = (float*)alloc(G4 * 4);
    u64* hbc_e   = (u64*)alloc(512 * 8);
    u64* hbc_d   = (u64*)alloc(512 * 8);
    u16* Hh      = (u16*)alloc((size_t)S_ENC * HDIM * 2);
    u16* HhT     = (u16*)alloc((size_t)HDIM * S_ENC * 2);
    u16* OutA    = (u16*)alloc((size_t)T_DEC * KFC * 2);
    float* scores = (float*)alloc((size_t)T_DEC * S_ENC * 4);
    u16* attn    = (u16*)alloc((size_t)T_DEC * S_ENC * 2);
    float* ctx   = (float*)alloc((size_t)T_DEC * HDIM * 4);

    k_init<<<2, 256, 0, stream>>>(hbc_e, hbc_d);
    k_bias<<<8, 256, 0, stream>>>(enc_bih, enc_bhh, dec_bih, dec_bhh, bias_e, bias_d);
    k_embed<<<S_TOT, 256, 0, stream>>>(loc, tim, clu, emb_loc, emb_tim, emb_clu, xb);
    // XW = x @ Wih^T + (bih+bhh)   (encoder rows then decoder rows)
    gemm_bt<true><<<dim3(G4 / 128, S_ENC / 128), 256, 0, stream>>>(
        xb, enc_Wih, XW, bias_e, G4, DDIM, DDIM, DDIM, G4);
    gemm_bt<true><<<dim3(G4 / 128, T_DEC / 128), 256, 0, stream>>>(
        xb + (size_t)S_ENC * DDIM, dec_Wih, XW + (size_t)S_ENC * G4, bias_d, G4, DDIM, DDIM, DDIM, G4);
    k_lstm<<<128, 256, 0, stream>>>(enc_Whh, dec_Whh, XW, hbc_e, hbc_d, Hh, HhT, OutA);
    // scores = Hs @ Hh^T
    gemm_bt<false><<<dim3(S_ENC / 128, T_DEC / 128), 256, 0, stream>>>(
        OutA, Hh, scores, nullptr, S_ENC, HDIM, KFC, HDIM, S_ENC);
    k_softmax<<<T_DEC, 256, 0, stream>>>(scores, attn);
    // context = attn @ Hh   (via HhT as Bt)
    gemm_bt<false><<<dim3(HDIM / 128, T_DEC / 128), 256, 0, stream>>>(
        attn, HhT, ctx, nullptr, HDIM, S_ENC, S_ENC, S_ENC, HDIM);
    k_finish<<<T_DEC, 256, 0, stream>>>(ctx, emb_uid, uid, OutA);
    // y = Out @ fcW^T + fcb   (fp32 fcW converted during staging), into d_out
    gemm_bt<true><<<dim3((NLOC + 127) / 128, T_DEC / 128), 256, 0, stream>>>(
        OutA, fcW, out, fcb, NLOC, KFC, KFC, KFC, NLOC);
    k_logsoftmax<<<T_DEC, 256, 0, stream>>>(out);
}